// Round 2
// 328.230 us; speedup vs baseline: 1.0990x; 1.0990x over previous
//
#include <hip/hip_runtime.h>

typedef unsigned short u16;
typedef __attribute__((ext_vector_type(4))) float f32x4;
typedef __attribute__((ext_vector_type(8))) short s16x8;
typedef __attribute__((ext_vector_type(8))) unsigned short u16x8;
typedef __attribute__((ext_vector_type(4))) unsigned short u16x4;

// round-to-nearest-even f32 -> bf16
__device__ __forceinline__ u16 f2b(float x) {
  union { float f; unsigned u; } v; v.f = x;
  unsigned r = v.u + 0x7fffu + ((v.u >> 16) & 1u);
  return (u16)(r >> 16);
}
__device__ __forceinline__ float b2f(u16 x) {
  union { unsigned u; float f; } v; v.u = ((unsigned)x) << 16;
  return v.f;
}

// ---------------- cast fp32 -> bf16, 3 inputs in one launch (grid.y selects) ----------------
__global__ __launch_bounds__(256) void cast3_f32_bf16(const float* __restrict__ s0,
                                                      const float* __restrict__ s1,
                                                      const float* __restrict__ s2,
                                                      u16* __restrict__ dst, long n4) {
  const float* src = (blockIdx.y == 0) ? s0 : ((blockIdx.y == 1) ? s1 : s2);
  long i = blockIdx.x * 256 + threadIdx.x;
  if (i >= n4) return;
  float4 f = ((const float4*)src)[i];
  u16x4 o;
  o.x = f2b(f.x); o.y = f2b(f.y); o.z = f2b(f.z); o.w = f2b(f.w);
  ((u16x4*)(dst + blockIdx.y * n4 * 4))[i] = o;
}

// ---------------- W[E,A] fp32 -> Wt[A,E] bf16, 3 weights in one launch ----------------
__global__ __launch_bounds__(256) void transpose_cast_w3(const float* __restrict__ w0,
                                                         const float* __restrict__ w1,
                                                         const float* __restrict__ w2,
                                                         u16* __restrict__ Wt, int E_, int A_) {
  __shared__ float tile[32][33];
  const float* W = (blockIdx.z == 0) ? w0 : ((blockIdx.z == 1) ? w1 : w2);
  u16* dst = Wt + (long)blockIdx.z * E_ * A_;
  int a0 = blockIdx.x * 32, e0 = blockIdx.y * 32;
  int tx = threadIdx.x & 31, ty = threadIdx.x >> 5;
  for (int i = ty; i < 32; i += 8) tile[i][tx] = W[(long)(e0 + i) * A_ + a0 + tx];
  __syncthreads();
  for (int i = ty; i < 32; i += 8) dst[(long)(a0 + i) * E_ + e0 + tx] = f2b(tile[tx][i]);
}

// ============================================================================================
// 256x256-tile 8-phase bf16 GEMM (T1+T2+T3+T4+T5, m201-style template, plain HIP):
//   C[M,N] = A[M,K] * B[N,K]^T * scale + bias
// 8 waves (2M x 4N), 512 threads, BK=64, LDS 128 KiB = 2 buf x (A[256][64] + B[256][64]).
// Per wave: 128x64 output = 8x4 16x16 frags; per phase: one 64x32 quadrant x K=64 = 16 MFMA.
// T2 swizzle: LDS[row][chunk] holds G[row][chunk ^ (row&7)] (16B chunks) -- applied by
// pre-swizzling the global_load_lds SOURCE (dest stays linear, m104/m173), XOR on ds_read.
// RACE-FREE stage schedule (re-derived; fixes the ph3/ph7 same-window write/read race):
// quadrant order (0,0)->(0,1)->(1,1)->(1,0) => buf A-regions last read ph3, B ph4. Stages:
//   ph1: B(kc+1)->buf1 | ph4: A(kc+2)->buf0 + vmcnt(4) | ph5: B(kc+2)->buf0
//   ph8: A(kc+3)->buf1 + vmcnt(4)
// Every restage is >=1 barrier after the last read of its destination's old data; every
// read is covered by a counted vmcnt >=3 phases after issue; never vmcnt(0) in main loop.
// z==2 + VtG: write output transposed into Vt via u16x4 (4 consecutive M-rows per lane).
// ============================================================================================
template<bool OUT_BF16>
__global__ __launch_bounds__(512, 2)
void gemm256(const u16* __restrict__ Ag, const u16* __restrict__ Bg,
             const float* __restrict__ b0, const float* __restrict__ b1,
             const float* __restrict__ b2, void* __restrict__ Cg,
             int gm, int K, int N, float scale,
             long sA, long sB, long sC,
             u16* __restrict__ VtG, long vtB, int vtS) {
  __shared__ u16 lds[65536];  // 128 KiB
  char* ldsc = (char*)lds;
  const int t = threadIdx.x;
  const int w = t >> 6, l = t & 63;
  const int wm = w >> 2, wn = w & 3;

  // T1: XCD-aware swizzle (grid.x % 8 == 0 for all our launches -> bijective)
  const int nwg = gridDim.x;
  const int Lb = blockIdx.x;
  const int chunk = nwg >> 3;
  const int id = (Lb & 7) * chunk + (Lb >> 3);
  const int im = id % gm, in = id / gm;
  const int m0 = im * 256, n0 = in * 256;
  const int z = blockIdx.z;
  const float* bias = (z == 0) ? b0 : ((z == 1) ? b1 : b2);

  const u16* Ab = Ag + (long)z * sA + (long)m0 * K;
  const u16* Bb = Bg + (long)z * sB + (long)n0 * K;

  // staging: thread covers LDS bytes h*8192 + w*1024 + l*16 per load op.
  // row = h*64 + w*8 + (l>>3); swizzled source col-chunk = ((l&7) ^ (l>>3)) * 8 elems
  // (row&7 == l>>3 for every h, since 64|8 rows per step).
  const long so0 = (long)(w * 8 + (l >> 3)) * K + (long)(((l & 7) ^ (l >> 3)) << 3);
  const int ldst0 = w << 10;

  // ds_read lane bases (byte offsets). desired col chunk = (l>>4) [+4 for kk=1],
  // stored at chunk ^ (row&7), row&7 == l&7 for all frag rows (16-multiples added).
  const int cb0 = ((l >> 4) ^ (l & 7)) << 4;
  const int arow = (l & 15) << 7;
  const int aoff0 = (wm << 14) + arow + cb0;                                   // A @ 0
  const int aoff1 = aoff0 ^ 64;
  const int boff0 = 32768 + ((wn >> 1) << 14) + ((wn & 1) << 13) + arow + cb0; // B @ 32K
  const int boff1 = boff0 ^ 64;

  f32x4 acc[8][4] = {};
  s16x8 af[4][2], bf[2][2];
  const int NT = K >> 6;
  const int NT2 = NT >> 1;

  // stage both 128-row halves of A (AB=0) or B (AB=1) for k-tile KT: 4 x global_load_lds.
#define STG2(AB, KT) do {                                                                    \
    const u16* _sp = ((AB) ? Bb : Ab) + ((long)(KT) << 6) + so0;                             \
    const int _lo = (((KT) & 1) << 16) + ((AB) << 15) + ldst0;                               \
    _Pragma("unroll") for (int _h = 0; _h < 4; ++_h)                                         \
      __builtin_amdgcn_global_load_lds(                                                      \
          (const __attribute__((address_space(1))) unsigned int*)(_sp + (long)_h * 64 * K),  \
          (__attribute__((address_space(3))) unsigned int*)(ldsc + _lo + _h * 8192),         \
          16, 0, 0);                                                                         \
  } while (0)

  // SAB: -1 = no stage, 0 = stage A(SKT), 1 = stage B(SKT). VMN: -1 none, else vmcnt(VMN).
#define PHASE(BUF, MH, NH, RDA_, RDB_, SAB, SKT, VMN) do {                                   \
    if (RDA_) {                                                                              \
      _Pragma("unroll") for (int i = 0; i < 4; ++i) {                                        \
        af[i][0] = *(const s16x8*)(ldsc + ((BUF) << 16) + ((MH) << 13) + (i << 11) + aoff0); \
        af[i][1] = *(const s16x8*)(ldsc + ((BUF) << 16) + ((MH) << 13) + (i << 11) + aoff1); \
      }                                                                                      \
    }                                                                                        \
    if (RDB_) {                                                                              \
      _Pragma("unroll") for (int j = 0; j < 2; ++j) {                                        \
        bf[j][0] = *(const s16x8*)(ldsc + ((BUF) << 16) + ((NH) << 12) + (j << 11) + boff0); \
        bf[j][1] = *(const s16x8*)(ldsc + ((BUF) << 16) + ((NH) << 12) + (j << 11) + boff1); \
      }                                                                                      \
    }                                                                                        \
    if ((SAB) == 0) STG2(0, SKT);                                                            \
    if ((SAB) == 1) STG2(1, SKT);                                                            \
    __builtin_amdgcn_s_barrier();                                                            \
    asm volatile("s_waitcnt lgkmcnt(0)" ::: "memory");                                       \
    __builtin_amdgcn_s_setprio(1);                                                           \
    _Pragma("unroll") for (int kk = 0; kk < 2; ++kk)                                         \
      _Pragma("unroll") for (int i = 0; i < 4; ++i)                                          \
        _Pragma("unroll") for (int j = 0; j < 2; ++j)                                        \
          acc[(MH) * 4 + i][(NH) * 2 + j] = __builtin_amdgcn_mfma_f32_16x16x32_bf16(         \
              af[i][kk], bf[j][kk], acc[(MH) * 4 + i][(NH) * 2 + j], 0, 0, 0);               \
    __builtin_amdgcn_s_setprio(0);                                                           \
    if ((VMN) == 4) asm volatile("s_waitcnt vmcnt(4)" ::: "memory");                         \
    if ((VMN) == 0) asm volatile("s_waitcnt vmcnt(0)" ::: "memory");                         \
    __builtin_amdgcn_s_barrier();                                                            \
  } while (0)

  // prologue: A(0), B(0) -> buf0; A(1) -> buf1.  vmcnt(4): k-tile 0 fully landed,
  // A(1) allowed in flight (first read at ph5, enforced by ph4's vmcnt(4)).
  STG2(0, 0); STG2(1, 0); STG2(0, 1);
  asm volatile("s_waitcnt vmcnt(4)" ::: "memory");
  __builtin_amdgcn_s_barrier();

  for (int i2 = 0; i2 < NT2 - 1; ++i2) {
    const int kb = 2 * i2 + 1, kn = 2 * i2 + 2, kn1 = 2 * i2 + 3;
    PHASE(0, 0, 0, 1, 1, 1, kb, -1);   // q(0,0) buf0 | stage B(kb)->buf1
    PHASE(0, 0, 1, 0, 1, -1, 0, -1);   // q(0,1)
    PHASE(0, 1, 1, 1, 0, -1, 0, -1);   // q(1,1)      (buf0 A last read here)
    PHASE(0, 1, 0, 0, 1, 0, kn, 4);    // q(1,0)      | stage A(kn)->buf0; vmcnt(4): k(kb) landed
    PHASE(1, 0, 0, 1, 1, 1, kn, -1);   // q(0,0) buf1 | stage B(kn)->buf0 (buf0 B last read ph4)
    PHASE(1, 0, 1, 0, 1, -1, 0, -1);   // q(0,1)
    PHASE(1, 1, 1, 1, 0, -1, 0, -1);   // q(1,1)      (buf1 A last read here)
    PHASE(1, 1, 0, 0, 1, 0, kn1, 4);   // q(1,0)      | stage A(kn1)->buf1; vmcnt(4): k(kn) landed
  }
  {  // peeled last iteration (k-tiles NT-2, NT-1): only B(NT-1) left to stage
    PHASE(0, 0, 0, 1, 1, 1, NT - 1, -1);
    PHASE(0, 0, 1, 0, 1, -1, 0, -1);
    PHASE(0, 1, 1, 1, 0, -1, 0, -1);
    PHASE(0, 1, 0, 0, 1, -1, 0, 0);    // drain: A(NT-1) (prev ph8) + B(NT-1) (ph1) landed
    PHASE(1, 0, 0, 1, 1, -1, 0, -1);
    PHASE(1, 0, 1, 0, 1, -1, 0, -1);
    PHASE(1, 1, 1, 1, 0, -1, 0, -1);
    PHASE(1, 1, 0, 0, 1, -1, 0, -1);
  }
#undef PHASE
#undef STG2

  // epilogue. 16x16 C/D frag: col = l&15, row = (l>>4)*4 + r  (m89-verified)
  float bj[4];
#pragma unroll
  for (int j = 0; j < 4; ++j) {
    int col = n0 + wn * 64 + j * 16 + (l & 15);
    bj[j] = bias ? bias[col] : 0.0f;
  }

  if (OUT_BF16 && VtG != nullptr && z == 2) {
    const int b = m0 / vtS, smod = m0 % vtS;
    u16* vbase = VtG + (long)b * vtB + smod + wm * 128 + ((l >> 4) << 2);
#pragma unroll
    for (int i8 = 0; i8 < 8; ++i8)
#pragma unroll
      for (int j = 0; j < 4; ++j) {
        int col = n0 + wn * 64 + j * 16 + (l & 15);
        u16x4 o;
#pragma unroll
        for (int r = 0; r < 4; ++r) o[r] = f2b(acc[i8][j][r] * scale + bj[j]);
        *(u16x4*)(vbase + (long)col * vtS + i8 * 16) = o;
      }
  } else {
    long rbase = (long)z * sC + (long)(m0 + wm * 128 + ((l >> 4) << 2)) * N + n0 + wn * 64 + (l & 15);
#pragma unroll
    for (int i8 = 0; i8 < 8; ++i8)
#pragma unroll
      for (int j = 0; j < 4; ++j)
#pragma unroll
        for (int r = 0; r < 4; ++r) {
          float v = acc[i8][j][r] * scale + bj[j];
          long ro = rbase + (long)(i8 * 16 + r) * N + j * 16;
          if (OUT_BF16) ((u16*)Cg)[ro] = f2b(v);
          else          ((float*)Cg)[ro] = v;
        }
  }
}

// ---------------- row softmax: bf16 [rows,2048] -> bf16 probs ----------------
__device__ __forceinline__ float wred_max(float x) {
  for (int o = 32; o > 0; o >>= 1) x = fmaxf(x, __shfl_xor(x, o));
  return x;
}
__device__ __forceinline__ float wred_sum(float x) {
  for (int o = 32; o > 0; o >>= 1) x += __shfl_xor(x, o);
  return x;
}

__global__ __launch_bounds__(256) void softmax_rows_bf16(const u16* __restrict__ S,
                                                         u16* __restrict__ P, int ncols) {
  long row = blockIdx.x;
  const u16x8* s8 = (const u16x8*)(S + row * (long)ncols);
  int t = threadIdx.x;
  int wave = t >> 6, lane = t & 63;
  u16x8 a = s8[t];
  float f[8];
#pragma unroll
  for (int i = 0; i < 8; i++) f[i] = b2f(a[i]);
  float m = f[0];
#pragma unroll
  for (int i = 1; i < 8; i++) m = fmaxf(m, f[i]);
  m = wred_max(m);
  __shared__ float redm[4], reds[4];
  if (lane == 0) redm[wave] = m;
  __syncthreads();
  m = fmaxf(fmaxf(redm[0], redm[1]), fmaxf(redm[2], redm[3]));

  float e[8], s = 0.f;
#pragma unroll
  for (int i = 0; i < 8; i++) { e[i] = __expf(f[i] - m); s += e[i]; }
  s = wred_sum(s);
  if (lane == 0) reds[wave] = s;
  __syncthreads();
  s = reds[0] + reds[1] + reds[2] + reds[3];
  float inv = 1.0f / s;

  u16x8 o;
#pragma unroll
  for (int i = 0; i < 8; i++) o[i] = f2b(e[i] * inv);
  ((u16x8*)(P + row * (long)ncols))[t] = o;
}

extern "C" void kernel_launch(void* const* d_in, const int* in_sizes, int n_in,
                              void* d_out, int out_size, void* d_ws, size_t ws_size,
                              hipStream_t stream) {
  const float* query = (const float*)d_in[0];
  const float* key_  = (const float*)d_in[1];
  const float* value = (const float*)d_in[2];
  const float* Wq = (const float*)d_in[3];
  const float* bq = (const float*)d_in[4];
  const float* Wk = (const float*)d_in[5];
  const float* bk = (const float*)d_in[6];
  const float* Wv = (const float*)d_in[7];
  const float* bv = (const float*)d_in[8];

  constexpr int B = 4, S = 2048, E = 1024, A = 1024;
  constexpr long MB = 1024 * 1024;
  char* ws = (char*)d_ws;
  // layout (MiB): Qb 0-16, Kb 16-32, (unused 32-48), Vt 48-64, P 64-96, Sc(bf16) 96-128.
  // transient bf16 casts X* at 96-144 are consumed by projections before Sc is written.
  // Wt (3 contiguous) at 144-150.
  u16* Qb  = (u16*)(ws + 0 * MB);
  u16* Kb  = (u16*)(ws + 16 * MB);
  u16* Vt  = (u16*)(ws + 48 * MB);
  u16* P   = (u16*)(ws + 64 * MB);
  u16* Sc  = (u16*)(ws + 96 * MB);
  u16* Xq  = (u16*)(ws + 96 * MB);  // z-stride 8M elems (16 MB)
  u16* WqT = (u16*)(ws + 144 * MB); // z-stride 1M elems (2 MB)

  const long n = (long)B * S * E;   // 8M activation elements per tensor
  const long n4 = n / 4;
  dim3 blk(256);
  dim3 blk5(512);

  // 1) cast q/k/v fp32 -> bf16 (one launch)
  cast3_f32_bf16<<<dim3(n4 / 256, 3), blk, 0, stream>>>(query, key_, value, Xq, n4);

  // 2) W[E,A] -> Wt[A,E] bf16, all three (one launch)
  transpose_cast_w3<<<dim3(A / 32, E / 32, 3), blk, 0, stream>>>(Wq, Wk, Wv, WqT, E, A);

  // 3) merged QKV projections: z=0->Qb, z=1->Kb, z=2->Vt (transposed u16x4 scatter).
  //    M=8192, N=1024, K=1024 per z; gm=32, gn=4 -> 128 blocks x 3.
  gemm256<true><<<dim3(128, 1, 3), blk5, 0, stream>>>(
      Xq, WqT, bq, bk, bv, Qb, 32, E, A, 1.0f,
      (long)8 * MB, (long)1 * MB, (long)8 * MB,
      Vt, (long)A * S, S);

  // 4) scores = Q K^T / sqrt(A) -> bf16, batched over B. M=N=2048, K=1024; gm=8 -> 64 blocks x 4.
  gemm256<true><<<dim3(64, 1, 4), blk5, 0, stream>>>(
      Qb, Kb, nullptr, nullptr, nullptr, Sc, 8, A, S, 0.03125f,
      (long)S * A, (long)S * A, (long)S * S, nullptr, 0, 1);

  // 5) softmax rows (bf16 in, bf16 out)
  softmax_rows_bf16<<<dim3(B * S), blk, 0, stream>>>(Sc, P, S);

  // 6) out = P V : A=P[S,S], B=Vt[A,S] -> fp32 d_out. M=2048, N=1024, K=2048; gm=8 -> 32 blocks x 4.
  gemm256<false><<<dim3(32, 1, 4), blk5, 0, stream>>>(
      P, Vt, nullptr, nullptr, nullptr, (float*)d_out, 8, S, A, 1.0f,
      (long)S * S, (long)S * A, (long)S * A, nullptr, 0, 1);
}

// Round 3
// 322.638 us; speedup vs baseline: 1.1181x; 1.0173x over previous
//
#include <hip/hip_runtime.h>

typedef unsigned short u16;
typedef __attribute__((ext_vector_type(4))) float f32x4;
typedef __attribute__((ext_vector_type(8))) short s16x8;
typedef __attribute__((ext_vector_type(8))) unsigned short u16x8;
typedef __attribute__((ext_vector_type(4))) unsigned short u16x4;

// round-to-nearest-even f32 -> bf16
__device__ __forceinline__ u16 f2b(float x) {
  union { float f; unsigned u; } v; v.f = x;
  unsigned r = v.u + 0x7fffu + ((v.u >> 16) & 1u);
  return (u16)(r >> 16);
}
__device__ __forceinline__ float b2f(u16 x) {
  union { unsigned u; float f; } v; v.u = ((unsigned)x) << 16;
  return v.f;
}

// ---------------- cast fp32 -> bf16, 3 inputs in one launch (grid.y selects) ----------------
__global__ __launch_bounds__(256) void cast3_f32_bf16(const float* __restrict__ s0,
                                                      const float* __restrict__ s1,
                                                      const float* __restrict__ s2,
                                                      u16* __restrict__ dst, long n4) {
  const float* src = (blockIdx.y == 0) ? s0 : ((blockIdx.y == 1) ? s1 : s2);
  long i = blockIdx.x * 256 + threadIdx.x;
  if (i >= n4) return;
  float4 f = ((const float4*)src)[i];
  u16x4 o;
  o.x = f2b(f.x); o.y = f2b(f.y); o.z = f2b(f.z); o.w = f2b(f.w);
  ((u16x4*)(dst + blockIdx.y * n4 * 4))[i] = o;
}

// ---------------- W[E,A] fp32 -> Wt[A,E] bf16, 3 weights in one launch ----------------
__global__ __launch_bounds__(256) void transpose_cast_w3(const float* __restrict__ w0,
                                                         const float* __restrict__ w1,
                                                         const float* __restrict__ w2,
                                                         u16* __restrict__ Wt, int E_, int A_) {
  __shared__ float tile[32][33];
  const float* W = (blockIdx.z == 0) ? w0 : ((blockIdx.z == 1) ? w1 : w2);
  u16* dst = Wt + (long)blockIdx.z * E_ * A_;
  int a0 = blockIdx.x * 32, e0 = blockIdx.y * 32;
  int tx = threadIdx.x & 31, ty = threadIdx.x >> 5;
  for (int i = ty; i < 32; i += 8) tile[i][tx] = W[(long)(e0 + i) * A_ + a0 + tx];
  __syncthreads();
  for (int i = ty; i < 32; i += 8) dst[(long)(a0 + i) * E_ + e0 + tx] = f2b(tile[tx][i]);
}

// ============================================================================================
// 256x256-tile 8-phase bf16 GEMM (T1+T2+T3+T4+T5):  C[M,N] = A[M,K]*B[N,K]^T * scale + bias
// 8 waves (2M x 4N), 512 threads, BK=64, LDS 128 KiB = 2 buf x (A[256][64] + B[256][64]).
// T2 swizzle: LDS[row][chunk] holds G[row][chunk ^ (row&7)] (16B chunks) -- via pre-swizzled
// global_load_lds SOURCE (dest linear, m104/m173), XOR on ds_read. Verified: conflicts = 0.
// R3 change vs R2 (the 26%-MfmaUtil post-mortem): removed the forced lgkmcnt(0) and the
// mid-phase barrier. ONE trailing barrier per phase; the compiler's counted lgkm waits
// interleave ds_reads into the MFMA stream (m97: compiler emits lgkmcnt(4/3/1/0) fine-
// grained; forcing 0 serialized read-drain vs MFMA and cost ~600 cyc/phase).
// Race-freedom under single barrier:
//  RAW: ph5/ph1 frag reads guarded by ph4/ph8-end vmcnt(4) + trailing barrier (asm memory
//       clobber also blocks read hoisting above the vmcnt).
//  WAR: every frag read is consumed by an MFMA in its phase -> counted waits complete all
//       reads before the last MFMA -> before trailing barrier -> before next-phase stages.
//       Stages at ph1/ph4/ph5/ph8 target regions last-read >=1 barrier earlier; all legal
//       cross-barrier read-hoists land in windows whose stages touch disjoint regions.
// z==2 + VtG: write output transposed into Vt via u16x4 (4 consecutive M-rows per lane).
// ============================================================================================
template<bool OUT_BF16>
__global__ __launch_bounds__(512, 2)
void gemm256(const u16* __restrict__ Ag, const u16* __restrict__ Bg,
             const float* __restrict__ b0, const float* __restrict__ b1,
             const float* __restrict__ b2, void* __restrict__ Cg,
             int gm, int K, int N, float scale,
             long sA, long sB, long sC,
             u16* __restrict__ VtG, long vtB, int vtS) {
  __shared__ u16 lds[65536];  // 128 KiB
  char* ldsc = (char*)lds;
  const int t = threadIdx.x;
  const int w = t >> 6, l = t & 63;
  const int wm = w >> 2, wn = w & 3;

  // T1: XCD-aware swizzle (grid.x % 8 == 0 for all our launches -> bijective)
  const int nwg = gridDim.x;
  const int Lb = blockIdx.x;
  const int chunk = nwg >> 3;
  const int id = (Lb & 7) * chunk + (Lb >> 3);
  const int im = id % gm, in = id / gm;
  const int m0 = im * 256, n0 = in * 256;
  const int z = blockIdx.z;
  const float* bias = (z == 0) ? b0 : ((z == 1) ? b1 : b2);

  const u16* Ab = Ag + (long)z * sA + (long)m0 * K;
  const u16* Bb = Bg + (long)z * sB + (long)n0 * K;

  // staging: thread covers LDS bytes h*8192 + w*1024 + l*16 per load op.
  // row = h*64 + w*8 + (l>>3); swizzled source col-chunk = ((l&7) ^ (l>>3)) * 8 elems.
  const long so0 = (long)(w * 8 + (l >> 3)) * K + (long)(((l & 7) ^ (l >> 3)) << 3);
  const int ldst0 = w << 10;

  // ds_read lane bases (byte offsets). desired col chunk = (l>>4) [+4 for kk=1],
  // stored at chunk ^ (row&7), row&7 == l&7 for all frag rows (16-multiples added).
  const int cb0 = ((l >> 4) ^ (l & 7)) << 4;
  const int arow = (l & 15) << 7;
  const int aoff0 = (wm << 14) + arow + cb0;                                   // A @ 0
  const int aoff1 = aoff0 ^ 64;
  const int boff0 = 32768 + ((wn >> 1) << 14) + ((wn & 1) << 13) + arow + cb0; // B @ 32K
  const int boff1 = boff0 ^ 64;

  f32x4 acc[8][4] = {};
  s16x8 af[4][2], bf[2][2];
  const int NT = K >> 6;
  const int NT2 = NT >> 1;

  // stage both 128-row halves of A (AB=0) or B (AB=1) for k-tile KT: 4 x global_load_lds.
#define STG2(AB, KT) do {                                                                    \
    const u16* _sp = ((AB) ? Bb : Ab) + ((long)(KT) << 6) + so0;                             \
    const int _lo = (((KT) & 1) << 16) + ((AB) << 15) + ldst0;                               \
    _Pragma("unroll") for (int _h = 0; _h < 4; ++_h)                                         \
      __builtin_amdgcn_global_load_lds(                                                      \
          (const __attribute__((address_space(1))) unsigned int*)(_sp + (long)_h * 64 * K),  \
          (__attribute__((address_space(3))) unsigned int*)(ldsc + _lo + _h * 8192),         \
          16, 0, 0);                                                                         \
  } while (0)

  // SAB: -1 = no stage, 0 = stage A(SKT), 1 = stage B(SKT). VMN: -1 none, else vmcnt(VMN).
  // Single trailing barrier; NO forced lgkmcnt -- compiler emits counted waits per frag use.
#define PHASE(BUF, MH, NH, RDA_, RDB_, SAB, SKT, VMN) do {                                   \
    if (RDA_) {                                                                              \
      _Pragma("unroll") for (int i = 0; i < 4; ++i) {                                        \
        af[i][0] = *(const s16x8*)(ldsc + ((BUF) << 16) + ((MH) << 13) + (i << 11) + aoff0); \
        af[i][1] = *(const s16x8*)(ldsc + ((BUF) << 16) + ((MH) << 13) + (i << 11) + aoff1); \
      }                                                                                      \
    }                                                                                        \
    if (RDB_) {                                                                              \
      _Pragma("unroll") for (int j = 0; j < 2; ++j) {                                        \
        bf[j][0] = *(const s16x8*)(ldsc + ((BUF) << 16) + ((NH) << 12) + (j << 11) + boff0); \
        bf[j][1] = *(const s16x8*)(ldsc + ((BUF) << 16) + ((NH) << 12) + (j << 11) + boff1); \
      }                                                                                      \
    }                                                                                        \
    if ((SAB) == 0) STG2(0, SKT);                                                            \
    if ((SAB) == 1) STG2(1, SKT);                                                            \
    __builtin_amdgcn_s_setprio(1);                                                           \
    _Pragma("unroll") for (int kk = 0; kk < 2; ++kk)                                         \
      _Pragma("unroll") for (int i = 0; i < 4; ++i)                                          \
        _Pragma("unroll") for (int j = 0; j < 2; ++j)                                        \
          acc[(MH) * 4 + i][(NH) * 2 + j] = __builtin_amdgcn_mfma_f32_16x16x32_bf16(         \
              af[i][kk], bf[j][kk], acc[(MH) * 4 + i][(NH) * 2 + j], 0, 0, 0);               \
    __builtin_amdgcn_s_setprio(0);                                                           \
    if ((VMN) == 4) asm volatile("s_waitcnt vmcnt(4)" ::: "memory");                         \
    if ((VMN) == 0) asm volatile("s_waitcnt vmcnt(0)" ::: "memory");                         \
    __builtin_amdgcn_s_barrier();                                                            \
  } while (0)

  // prologue: A(0), B(0) -> buf0; A(1) -> buf1.  vmcnt(4): k-tile 0 fully landed,
  // A(1) allowed in flight (first read at ph5, enforced by ph4's vmcnt(4)).
  STG2(0, 0); STG2(1, 0); STG2(0, 1);
  asm volatile("s_waitcnt vmcnt(4)" ::: "memory");
  __builtin_amdgcn_s_barrier();

  for (int i2 = 0; i2 < NT2 - 1; ++i2) {
    const int kb = 2 * i2 + 1, kn = 2 * i2 + 2, kn1 = 2 * i2 + 3;
    PHASE(0, 0, 0, 1, 1, 1, kb, -1);   // q(0,0) buf0 | stage B(kb)->buf1
    PHASE(0, 0, 1, 0, 1, -1, 0, -1);   // q(0,1)
    PHASE(0, 1, 1, 1, 0, -1, 0, -1);   // q(1,1)      (buf0 A last read here)
    PHASE(0, 1, 0, 0, 1, 0, kn, 4);    // q(1,0)      | stage A(kn)->buf0; vmcnt(4): k(kb) landed
    PHASE(1, 0, 0, 1, 1, 1, kn, -1);   // q(0,0) buf1 | stage B(kn)->buf0 (buf0 B last read ph4)
    PHASE(1, 0, 1, 0, 1, -1, 0, -1);   // q(0,1)
    PHASE(1, 1, 1, 1, 0, -1, 0, -1);   // q(1,1)      (buf1 A last read here)
    PHASE(1, 1, 0, 0, 1, 0, kn1, 4);   // q(1,0)      | stage A(kn1)->buf1; vmcnt(4): k(kn) landed
  }
  {  // peeled last iteration (k-tiles NT-2, NT-1): only B(NT-1) left to stage
    PHASE(0, 0, 0, 1, 1, 1, NT - 1, -1);
    PHASE(0, 0, 1, 0, 1, -1, 0, -1);
    PHASE(0, 1, 1, 1, 0, -1, 0, -1);
    PHASE(0, 1, 0, 0, 1, -1, 0, 0);    // drain: A(NT-1) (prev ph8) + B(NT-1) (ph1) landed
    PHASE(1, 0, 0, 1, 1, -1, 0, -1);
    PHASE(1, 0, 1, 0, 1, -1, 0, -1);
    PHASE(1, 1, 1, 1, 0, -1, 0, -1);
    PHASE(1, 1, 0, 0, 1, -1, 0, -1);
  }
#undef PHASE
#undef STG2

  // epilogue. 16x16 C/D frag: col = l&15, row = (l>>4)*4 + r  (m89-verified)
  float bj[4];
#pragma unroll
  for (int j = 0; j < 4; ++j) {
    int col = n0 + wn * 64 + j * 16 + (l & 15);
    bj[j] = bias ? bias[col] : 0.0f;
  }

  if (OUT_BF16 && VtG != nullptr && z == 2) {
    const int b = m0 / vtS, smod = m0 % vtS;
    u16* vbase = VtG + (long)b * vtB + smod + wm * 128 + ((l >> 4) << 2);
#pragma unroll
    for (int i8 = 0; i8 < 8; ++i8)
#pragma unroll
      for (int j = 0; j < 4; ++j) {
        int col = n0 + wn * 64 + j * 16 + (l & 15);
        u16x4 o;
#pragma unroll
        for (int r = 0; r < 4; ++r) o[r] = f2b(acc[i8][j][r] * scale + bj[j]);
        *(u16x4*)(vbase + (long)col * vtS + i8 * 16) = o;
      }
  } else {
    long rbase = (long)z * sC + (long)(m0 + wm * 128 + ((l >> 4) << 2)) * N + n0 + wn * 64 + (l & 15);
#pragma unroll
    for (int i8 = 0; i8 < 8; ++i8)
#pragma unroll
      for (int j = 0; j < 4; ++j)
#pragma unroll
        for (int r = 0; r < 4; ++r) {
          float v = acc[i8][j][r] * scale + bj[j];
          long ro = rbase + (long)(i8 * 16 + r) * N + j * 16;
          if (OUT_BF16) ((u16*)Cg)[ro] = f2b(v);
          else          ((float*)Cg)[ro] = v;
        }
  }
}

// ---------------- row softmax: bf16 [rows,2048] -> bf16 probs ----------------
__device__ __forceinline__ float wred_max(float x) {
  for (int o = 32; o > 0; o >>= 1) x = fmaxf(x, __shfl_xor(x, o));
  return x;
}
__device__ __forceinline__ float wred_sum(float x) {
  for (int o = 32; o > 0; o >>= 1) x += __shfl_xor(x, o);
  return x;
}

__global__ __launch_bounds__(256) void softmax_rows_bf16(const u16* __restrict__ S,
                                                         u16* __restrict__ P, int ncols) {
  long row = blockIdx.x;
  const u16x8* s8 = (const u16x8*)(S + row * (long)ncols);
  int t = threadIdx.x;
  int wave = t >> 6, lane = t & 63;
  u16x8 a = s8[t];
  float f[8];
#pragma unroll
  for (int i = 0; i < 8; i++) f[i] = b2f(a[i]);
  float m = f[0];
#pragma unroll
  for (int i = 1; i < 8; i++) m = fmaxf(m, f[i]);
  m = wred_max(m);
  __shared__ float redm[4], reds[4];
  if (lane == 0) redm[wave] = m;
  __syncthreads();
  m = fmaxf(fmaxf(redm[0], redm[1]), fmaxf(redm[2], redm[3]));

  float e[8], s = 0.f;
#pragma unroll
  for (int i = 0; i < 8; i++) { e[i] = __expf(f[i] - m); s += e[i]; }
  s = wred_sum(s);
  if (lane == 0) reds[wave] = s;
  __syncthreads();
  s = reds[0] + reds[1] + reds[2] + reds[3];
  float inv = 1.0f / s;

  u16x8 o;
#pragma unroll
  for (int i = 0; i < 8; i++) o[i] = f2b(e[i] * inv);
  ((u16x8*)(P + row * (long)ncols))[t] = o;
}

extern "C" void kernel_launch(void* const* d_in, const int* in_sizes, int n_in,
                              void* d_out, int out_size, void* d_ws, size_t ws_size,
                              hipStream_t stream) {
  const float* query = (const float*)d_in[0];
  const float* key_  = (const float*)d_in[1];
  const float* value = (const float*)d_in[2];
  const float* Wq = (const float*)d_in[3];
  const float* bq = (const float*)d_in[4];
  const float* Wk = (const float*)d_in[5];
  const float* bk = (const float*)d_in[6];
  const float* Wv = (const float*)d_in[7];
  const float* bv = (const float*)d_in[8];

  constexpr int B = 4, S = 2048, E = 1024, A = 1024;
  constexpr long MB = 1024 * 1024;
  char* ws = (char*)d_ws;
  // layout (MiB): Qb 0-16, Kb 16-32, (unused 32-48), Vt 48-64, P 64-96, Sc(bf16) 96-128.
  // transient bf16 casts X* at 96-144 are consumed by projections before Sc is written.
  // Wt (3 contiguous) at 144-150.
  u16* Qb  = (u16*)(ws + 0 * MB);
  u16* Kb  = (u16*)(ws + 16 * MB);
  u16* Vt  = (u16*)(ws + 48 * MB);
  u16* P   = (u16*)(ws + 64 * MB);
  u16* Sc  = (u16*)(ws + 96 * MB);
  u16* Xq  = (u16*)(ws + 96 * MB);  // z-stride 8M elems (16 MB)
  u16* WqT = (u16*)(ws + 144 * MB); // z-stride 1M elems (2 MB)

  const long n = (long)B * S * E;   // 8M activation elements per tensor
  const long n4 = n / 4;
  dim3 blk(256);
  dim3 blk5(512);

  // 1) cast q/k/v fp32 -> bf16 (one launch)
  cast3_f32_bf16<<<dim3(n4 / 256, 3), blk, 0, stream>>>(query, key_, value, Xq, n4);

  // 2) W[E,A] -> Wt[A,E] bf16, all three (one launch)
  transpose_cast_w3<<<dim3(A / 32, E / 32, 3), blk, 0, stream>>>(Wq, Wk, Wv, WqT, E, A);

  // 3) merged QKV projections: z=0->Qb, z=1->Kb, z=2->Vt (transposed u16x4 scatter).
  //    M=8192, N=1024, K=1024 per z; gm=32, gn=4 -> 128 blocks x 3.
  gemm256<true><<<dim3(128, 1, 3), blk5, 0, stream>>>(
      Xq, WqT, bq, bk, bv, Qb, 32, E, A, 1.0f,
      (long)8 * MB, (long)1 * MB, (long)8 * MB,
      Vt, (long)A * S, S);

  // 4) scores = Q K^T / sqrt(A) -> bf16, batched over B. M=N=2048, K=1024; gm=8 -> 64 blocks x 4.
  gemm256<true><<<dim3(64, 1, 4), blk5, 0, stream>>>(
      Qb, Kb, nullptr, nullptr, nullptr, Sc, 8, A, S, 0.03125f,
      (long)S * A, (long)S * A, (long)S * S, nullptr, 0, 1);

  // 5) softmax rows (bf16 in, bf16 out)
  softmax_rows_bf16<<<dim3(B * S), blk, 0, stream>>>(Sc, P, S);

  // 6) out = P V : A=P[S,S], B=Vt[A,S] -> fp32 d_out. M=2048, N=1024, K=2048; gm=8 -> 32 blocks x 4.
  gemm256<false><<<dim3(32, 1, 4), blk5, 0, stream>>>(
      P, Vt, nullptr, nullptr, nullptr, (float*)d_out, 8, S, A, 1.0f,
      (long)S * S, (long)S * A, (long)S * A, nullptr, 0, 1);
}

// Round 4
// 312.935 us; speedup vs baseline: 1.1527x; 1.0310x over previous
//
#include <hip/hip_runtime.h>

typedef unsigned short u16;
typedef __attribute__((ext_vector_type(4))) float f32x4;
typedef __attribute__((ext_vector_type(8))) short s16x8;
typedef __attribute__((ext_vector_type(8))) unsigned short u16x8;
typedef __attribute__((ext_vector_type(4))) unsigned short u16x4;

// round-to-nearest-even f32 -> bf16
__device__ __forceinline__ u16 f2b(float x) {
  union { float f; unsigned u; } v; v.f = x;
  unsigned r = v.u + 0x7fffu + ((v.u >> 16) & 1u);
  return (u16)(r >> 16);
}
__device__ __forceinline__ float b2f(u16 x) {
  union { unsigned u; float f; } v; v.u = ((unsigned)x) << 16;
  return v.f;
}

// ---------------- cast fp32 -> bf16, 3 inputs in one launch (grid.y selects) ----------------
__global__ __launch_bounds__(256) void cast3_f32_bf16(const float* __restrict__ s0,
                                                      const float* __restrict__ s1,
                                                      const float* __restrict__ s2,
                                                      u16* __restrict__ dst, long n4) {
  const float* src = (blockIdx.y == 0) ? s0 : ((blockIdx.y == 1) ? s1 : s2);
  long i = blockIdx.x * 256 + threadIdx.x;
  if (i >= n4) return;
  float4 f = ((const float4*)src)[i];
  u16x4 o;
  o.x = f2b(f.x); o.y = f2b(f.y); o.z = f2b(f.z); o.w = f2b(f.w);
  ((u16x4*)(dst + blockIdx.y * n4 * 4))[i] = o;
}

// ---------------- W[E,A] fp32 -> Wt[A,E] bf16, 3 weights in one launch ----------------
__global__ __launch_bounds__(256) void transpose_cast_w3(const float* __restrict__ w0,
                                                         const float* __restrict__ w1,
                                                         const float* __restrict__ w2,
                                                         u16* __restrict__ Wt, int E_, int A_) {
  __shared__ float tile[32][33];
  const float* W = (blockIdx.z == 0) ? w0 : ((blockIdx.z == 1) ? w1 : w2);
  u16* dst = Wt + (long)blockIdx.z * E_ * A_;
  int a0 = blockIdx.x * 32, e0 = blockIdx.y * 32;
  int tx = threadIdx.x & 31, ty = threadIdx.x >> 5;
  for (int i = ty; i < 32; i += 8) tile[i][tx] = W[(long)(e0 + i) * A_ + a0 + tx];
  __syncthreads();
  for (int i = ty; i < 32; i += 8) dst[(long)(a0 + i) * E_ + e0 + tx] = f2b(tile[tx][i]);
}

// ============================================================================================
// 256xBN-tile bf16 GEMM, BK=32, ring-4 LDS, 2 phases per k-tile:
//   C[M,N] = A[M,K]*B[N,K]^T * scale + bias
// 8 waves (2M x 4N), 512 threads. Per wave: 128 x (BN/4) output.
// R4 design (post-mortem of 1400cyc/phase zero-overlap serial sum at the 256-reg wall):
//  - Phase = one 64-row M-half x full per-wave N: B frags read ONCE per k-tile and held
//    (bf[J] regs), reads minimal (24 b128/wave per 64k at BN=256), frag regs 32 VGPR.
//  - Ring-4 buffers: stage tile t+3 during tile t (2 ops ph_even=A, 1-2 ops ph_odd=B);
//    counted vmcnt(2*OPS) once per k-tile, never 0 in main loop; ~3-tile (>2000cyc) lead.
//    WAR: buffer restaged (ph_even(t+1)) exactly one barrier after last read (ph_odd(t)).
//  - Swizzle for 64B rows: chunk ^= (row>>1)&3. Bank enumeration: 16 lanes -> 2/bank
//    uniform = free (m136). Stage-side: source chunk pre-XOR, LDS dest linear (m104/m173).
//  - ONE trailing barrier per phase; compiler emits counted lgkm waits for frag reads.
// BN=128 variant: PV grid 128->256 blocks (machine was half idle).
// z==2 + VtG (BN=256): write output transposed into Vt via u16x4.
// ============================================================================================
template<int BN, bool OUT_BF16>
__global__ __launch_bounds__(512, 2)
void gemmK32(const u16* __restrict__ Ag, const u16* __restrict__ Bg,
             const float* __restrict__ b0, const float* __restrict__ b1,
             const float* __restrict__ b2, void* __restrict__ Cg,
             int gn, int K, int N, float scale,
             long sA, long sB, long sC,
             u16* __restrict__ VtG, long vtB, int vtS) {
  constexpr int J = BN / 64;            // B frags per wave
  constexpr int WN = BN / 4;            // per-wave N extent
  constexpr int OPS = 2 + BN / 128;     // global_load_lds ops per k-tile (A:2 + B:1|2)
  constexpr int BUFSZ = (256 + BN) * 64;  // bytes per ring buffer (A 16KB + B BN*64B)
  __shared__ __align__(128) char ldsc[4 * BUFSZ];

  const int t = threadIdx.x;
  const int w = t >> 6, l = t & 63;
  const int wm = w >> 2, wn = w & 3;

  // T1: XCD-aware swizzle (grid.x % 8 == 0 -> bijective). Consecutive ids share im (A-panel).
  const int nwg = gridDim.x;
  const int Lb = blockIdx.x;
  const int chunk = nwg >> 3;
  const int id = (Lb & 7) * chunk + (Lb >> 3);
  const int im = id / gn, in = id % gn;
  const int m0 = im * 256, n0 = in * BN;
  const int z = blockIdx.z;
  const float* bias = (z == 0) ? b0 : ((z == 1) ? b1 : b2);

  const u16* Ab = Ag + (long)z * sA + (long)m0 * K;
  const u16* Bb = Bg + (long)z * sB + (long)n0 * K;

  // staging: per op (8KB, 128 rows x 64B), thread covers dest byte t*16 (linear).
  // dest row = t>>2, dest chunk = t&3; source chunk = (t&3) ^ ((row>>1)&3) = (t&3)^((t>>3)&3).
  const long so0 = (long)(t >> 2) * K + (long)(((t & 3) ^ ((t >> 3) & 3)) << 3);
  const int d16 = t * 16;

  // ds_read lane bases. desired chunk c = l>>4; stored at c ^ ((row>>1)&3), and for frag
  // rows (16a + (l&15)) that XOR term == (l>>1)&3 (lane-constant).
  const int cbR = ((l >> 4) ^ ((l >> 1) & 3)) << 4;
  const int aB = (wm << 13) + ((l & 15) << 6) + cbR;                 // within A region
  const int bB = 16384 + wn * (WN * 64) + ((l & 15) << 6) + cbR;     // within buffer

  f32x4 acc[8][J] = {};
  s16x8 af[4], bf[J];
  const int NTt = K >> 5;  // 32-wide k-tiles (NTt >= 4 required; K >= 1024 here)

#define GLD(SRC, DST)                                                                        \
  __builtin_amdgcn_global_load_lds(                                                         \
      (const __attribute__((address_space(1))) unsigned int*)(SRC),                         \
      (__attribute__((address_space(3))) unsigned int*)(DST), 16, 0, 0)

#define STGA(TT) do {                                                                        \
    const u16* _s = Ab + ((long)(TT) << 5) + so0;                                            \
    char* _d = ldsc + ((TT) & 3) * BUFSZ + d16;                                              \
    GLD(_s, _d);                                                                             \
    GLD(_s + (long)128 * K, _d + 8192);                                                      \
  } while (0)

#define STGB(TT) do {                                                                        \
    const u16* _s = Bb + ((long)(TT) << 5) + so0;                                            \
    char* _d = ldsc + ((TT) & 3) * BUFSZ + 16384 + d16;                                      \
    GLD(_s, _d);                                                                             \
    if (BN == 256) GLD(_s + (long)128 * K, _d + 8192);                                       \
  } while (0)

  // prologue: stage tiles 0,1,2; wait until tile 0 fully landed (<= 2*OPS outstanding).
  STGA(0); STGB(0); STGA(1); STGB(1); STGA(2); STGB(2);
  if (OPS == 4) asm volatile("s_waitcnt vmcnt(8)" ::: "memory");
  else          asm volatile("s_waitcnt vmcnt(6)" ::: "memory");
  __builtin_amdgcn_s_barrier();

  for (int tt = 0; tt < NTt; ++tt) {
    const int base = (tt & 3) * BUFSZ;
    // ---- phase even: read A half MH0 + all B frags; stage A(tt+3); MFMA rows 0-63 ----
#pragma unroll
    for (int i = 0; i < 4; ++i) af[i] = *(const s16x8*)(ldsc + base + aB + (i << 10));
#pragma unroll
    for (int j = 0; j < J; ++j) bf[j] = *(const s16x8*)(ldsc + base + bB + (j << 10));
    if (tt + 3 < NTt) STGA(tt + 3);
    __builtin_amdgcn_s_setprio(1);
#pragma unroll
    for (int i = 0; i < 4; ++i)
#pragma unroll
      for (int j = 0; j < J; ++j)
        acc[i][j] = __builtin_amdgcn_mfma_f32_16x16x32_bf16(af[i], bf[j], acc[i][j], 0, 0, 0);
    __builtin_amdgcn_s_setprio(0);
    __builtin_amdgcn_s_barrier();

    // ---- phase odd: read A half MH1 (+64 rows = 4096B); stage B(tt+3); MFMA rows 64-127 ----
#pragma unroll
    for (int i = 0; i < 4; ++i) af[i] = *(const s16x8*)(ldsc + base + aB + 4096 + (i << 10));
    if (tt + 3 < NTt) STGB(tt + 3);
    __builtin_amdgcn_s_setprio(1);
#pragma unroll
    for (int i = 0; i < 4; ++i)
#pragma unroll
      for (int j = 0; j < J; ++j)
        acc[4 + i][j] = __builtin_amdgcn_mfma_f32_16x16x32_bf16(af[i], bf[j], acc[4 + i][j], 0, 0, 0);
    __builtin_amdgcn_s_setprio(0);
    // counted wait: leave only tiles {tt+2, tt+3} (those staged) in flight -> tt+1 landed.
    if (tt <= NTt - 4) {
      if (OPS == 4) asm volatile("s_waitcnt vmcnt(8)" ::: "memory");
      else          asm volatile("s_waitcnt vmcnt(6)" ::: "memory");
    } else if (tt == NTt - 3) {
      if (OPS == 4) asm volatile("s_waitcnt vmcnt(4)" ::: "memory");
      else          asm volatile("s_waitcnt vmcnt(3)" ::: "memory");
    } else if (tt == NTt - 2) {
      asm volatile("s_waitcnt vmcnt(0)" ::: "memory");
    }
    __builtin_amdgcn_s_barrier();
  }
#undef STGA
#undef STGB
#undef GLD

  // epilogue. 16x16 C/D frag: col = l&15, row = (l>>4)*4 + r  (m89-verified)
  float bj[J];
#pragma unroll
  for (int j = 0; j < J; ++j) {
    int col = n0 + wn * WN + j * 16 + (l & 15);
    bj[j] = bias ? bias[col] : 0.0f;
  }

  if (OUT_BF16 && VtG != nullptr && z == 2) {
    const int b = m0 / vtS, smod = m0 % vtS;
    u16* vbase = VtG + (long)b * vtB + smod + wm * 128 + ((l >> 4) << 2);
#pragma unroll
    for (int i8 = 0; i8 < 8; ++i8)
#pragma unroll
      for (int j = 0; j < J; ++j) {
        int col = n0 + wn * WN + j * 16 + (l & 15);
        u16x4 o;
#pragma unroll
        for (int r = 0; r < 4; ++r) o[r] = f2b(acc[i8][j][r] * scale + bj[j]);
        *(u16x4*)(vbase + (long)col * vtS + i8 * 16) = o;
      }
  } else {
    long rbase = (long)z * sC + (long)(m0 + wm * 128 + ((l >> 4) << 2)) * N + n0 + wn * WN + (l & 15);
#pragma unroll
    for (int i8 = 0; i8 < 8; ++i8)
#pragma unroll
      for (int j = 0; j < J; ++j)
#pragma unroll
        for (int r = 0; r < 4; ++r) {
          float v = acc[i8][j][r] * scale + bj[j];
          long ro = rbase + (long)(i8 * 16 + r) * N + j * 16;
          if (OUT_BF16) ((u16*)Cg)[ro] = f2b(v);
          else          ((float*)Cg)[ro] = v;
        }
  }
}

// ---------------- row softmax: bf16 [rows,2048] -> bf16 probs ----------------
__device__ __forceinline__ float wred_max(float x) {
  for (int o = 32; o > 0; o >>= 1) x = fmaxf(x, __shfl_xor(x, o));
  return x;
}
__device__ __forceinline__ float wred_sum(float x) {
  for (int o = 32; o > 0; o >>= 1) x += __shfl_xor(x, o);
  return x;
}

__global__ __launch_bounds__(256) void softmax_rows_bf16(const u16* __restrict__ S,
                                                         u16* __restrict__ P, int ncols) {
  long row = blockIdx.x;
  const u16x8* s8 = (const u16x8*)(S + row * (long)ncols);
  int t = threadIdx.x;
  int wave = t >> 6, lane = t & 63;
  u16x8 a = s8[t];
  float f[8];
#pragma unroll
  for (int i = 0; i < 8; i++) f[i] = b2f(a[i]);
  float m = f[0];
#pragma unroll
  for (int i = 1; i < 8; i++) m = fmaxf(m, f[i]);
  m = wred_max(m);
  __shared__ float redm[4], reds[4];
  if (lane == 0) redm[wave] = m;
  __syncthreads();
  m = fmaxf(fmaxf(redm[0], redm[1]), fmaxf(redm[2], redm[3]));

  float e[8], s = 0.f;
#pragma unroll
  for (int i = 0; i < 8; i++) { e[i] = __expf(f[i] - m); s += e[i]; }
  s = wred_sum(s);
  if (lane == 0) reds[wave] = s;
  __syncthreads();
  s = reds[0] + reds[1] + reds[2] + reds[3];
  float inv = 1.0f / s;

  u16x8 o;
#pragma unroll
  for (int i = 0; i < 8; i++) o[i] = f2b(e[i] * inv);
  ((u16x8*)(P + row * (long)ncols))[t] = o;
}

extern "C" void kernel_launch(void* const* d_in, const int* in_sizes, int n_in,
                              void* d_out, int out_size, void* d_ws, size_t ws_size,
                              hipStream_t stream) {
  const float* query = (const float*)d_in[0];
  const float* key_  = (const float*)d_in[1];
  const float* value = (const float*)d_in[2];
  const float* Wq = (const float*)d_in[3];
  const float* bq = (const float*)d_in[4];
  const float* Wk = (const float*)d_in[5];
  const float* bk = (const float*)d_in[6];
  const float* Wv = (const float*)d_in[7];
  const float* bv = (const float*)d_in[8];

  constexpr int B = 4, S = 2048, E = 1024, A = 1024;
  constexpr long MB = 1024 * 1024;
  char* ws = (char*)d_ws;
  // layout (MiB): Qb 0-16, Kb 16-32, (unused 32-48), Vt 48-64, P 64-96, Sc(bf16) 96-128.
  // transient bf16 casts X* at 96-144 are consumed by projections before Sc is written.
  // Wt (3 contiguous) at 144-150.
  u16* Qb  = (u16*)(ws + 0 * MB);
  u16* Kb  = (u16*)(ws + 16 * MB);
  u16* Vt  = (u16*)(ws + 48 * MB);
  u16* P   = (u16*)(ws + 64 * MB);
  u16* Sc  = (u16*)(ws + 96 * MB);
  u16* Xq  = (u16*)(ws + 96 * MB);  // z-stride 8M elems (16 MB)
  u16* WqT = (u16*)(ws + 144 * MB); // z-stride 1M elems (2 MB)

  const long n = (long)B * S * E;   // 8M activation elements per tensor
  const long n4 = n / 4;
  dim3 blk(256);

  // 1) cast q/k/v fp32 -> bf16 (one launch)
  cast3_f32_bf16<<<dim3(n4 / 256, 3), blk, 0, stream>>>(query, key_, value, Xq, n4);

  // 2) W[E,A] -> Wt[A,E] bf16, all three (one launch)
  transpose_cast_w3<<<dim3(A / 32, E / 32, 3), blk, 0, stream>>>(Wq, Wk, Wv, WqT, E, A);

  // 3) merged QKV projections: z=0->Qb, z=1->Kb, z=2->Vt (transposed u16x4 scatter).
  //    M=8192, N=1024, K=1024 per z; gm=32, gn=4 -> 128 blocks x 3.
  gemmK32<256, true><<<dim3(128, 1, 3), dim3(512), 0, stream>>>(
      Xq, WqT, bq, bk, bv, Qb, 4, E, A, 1.0f,
      (long)8 * MB, (long)1 * MB, (long)8 * MB,
      Vt, (long)A * S, S);

  // 4) scores = Q K^T / sqrt(A) -> bf16, batched over B. M=N=2048, K=1024; 8x8 -> 64 blocks x 4.
  gemmK32<256, true><<<dim3(64, 1, 4), dim3(512), 0, stream>>>(
      Qb, Kb, nullptr, nullptr, nullptr, Sc, 8, A, S, 0.03125f,
      (long)S * A, (long)S * A, (long)S * S, nullptr, 0, 1);

  // 5) softmax rows (bf16 in, bf16 out)
  softmax_rows_bf16<<<dim3(B * S), blk, 0, stream>>>(Sc, P, S);

  // 6) out = P V : A=P[S,S], B=Vt[A,S] -> fp32 d_out. M=2048,N=1024,K=2048; BN=128:
  //    8x8 -> 64 blocks x 4 = 256 blocks (machine-filling; was 128 at BN=256).
  gemmK32<128, false><<<dim3(64, 1, 4), dim3(512), 0, stream>>>(
      P, Vt, nullptr, nullptr, nullptr, (float*)d_out, 8, S, A, 1.0f,
      (long)S * S, (long)S * A, (long)S * A, nullptr, 0, 1);
}